// Round 18
// baseline (103.224 us; speedup 1.0000x reference)
//
#include <hip/hip_runtime.h>

#define GRID_H 20
#define GRID_W 80
#define NCH 264
#define K 256
#define NPIX 128   // 16x8 glyph pixels

typedef __attribute__((ext_vector_type(8))) short short8;
typedef __attribute__((ext_vector_type(4))) float f32x4;
typedef __attribute__((ext_vector_type(8))) unsigned short u16x8;

static __device__ __forceinline__ unsigned short f2bf(float f) {
    unsigned int u = __builtin_bit_cast(unsigned int, f);
    u += 0x7FFFu + ((u >> 16) & 1u);   // round-to-nearest-even
    return (unsigned short)(u >> 16);
}

// Swizzled byte offset within a 32KB pixel-half (R9/R12-proven layout):
// 64 rows (local pixel) x 512B (256 bf16 channels), XOR (pl&7)<<4.
static __device__ __forceinline__ int bswz(int pl, int clbyte) {
    return (pl * 512 + clbyte) ^ ((pl & 7) << 4);
}

// Pack cm (f32 [256 ch][128 px]) -> ws: two 32KB pixel-halves whose LINEAR
// byte order equals the main kernel's swizzled LDS layout (R12/R16-proven).
__global__ void prep_kernel(const float* __restrict__ cm,
                            unsigned short* __restrict__ ws) {
    int i = blockIdx.x * 256 + threadIdx.x;   // 0..4095 chunks of 16B
    int p  = i & 127;                         // pixel 0..127
    int c8 = i >> 7;                          // channel-group of 8 (0..31)
    int hf = p >> 6, pl = p & 63;
    u16x8 pk;
    #pragma unroll
    for (int j = 0; j < 8; ++j) pk[j] = f2bf(cm[(c8 * 8 + j) * NPIX + p]);
    *reinterpret_cast<u16x8*>((char*)ws + hf * 32768 + bswz(pl, c8 * 16)) = pk;
}

// NOTE: plain 1-arg launch_bounds only. The 2-arg form (min waves/EU)
// miscompiled MFMA accumulation in R2/R3/R7. Single-distant-barrier DMA
// staging (R17) is racy — every DMA batch gets its own nearby barrier.
template <bool USE_WS>
__global__ __launch_bounds__(320) void ansi_kernel(
        const float* __restrict__ data,
        const float* __restrict__ cm,
        const unsigned short* __restrict__ ws,
        float* __restrict__ out) {
    // Double-buffered pixel-halves of B (R12 layout each).
    __shared__ alignas(16) unsigned char ldsB[2][32768];
    // Wave-PRIVATE epilogue staging (R9-proven): [wave][line][slot][x*3+ch]
    __shared__ alignas(16) float S[5][2][16][24];   // 15 KB; total 80896 B

    const int blk = blockIdx.x;          // 0..1279
    const int b  = blk / 10;             // batch
    const int rp = blk % 10;             // row-pair
    const int h0 = rp * 2;
    const float* dbase0 = data + (size_t)(b * GRID_H + h0) * GRID_W * NCH;
    const float* dbase1 = dbase0 + (size_t)GRID_W * NCH;
    const int t = threadIdx.x;
    const int wave = t >> 6;
    const int lane = t & 63;
    const int mrow = lane & 15;     // cell within M-tile
    const int g    = lane >> 4;     // k-group
    const int cell0 = wave * 16;

    // ---- issue DMA for half 0 -> buf0 (R12-proven shape) ----
    if (USE_WS) {
        const char* src = (const char*)ws;
        #pragma unroll
        for (int it = 0; it < 6; ++it) {
            int j = it * 320 + t;
            __builtin_amdgcn_global_load_lds(
                (const __attribute__((address_space(1))) void*)(src + (size_t)j * 16),
                (__attribute__((address_space(3))) void*)&ldsB[0][(it * 320 + wave * 64) * 16],
                16, 0, 0);
        }
        if (t < 128) {
            int j = 1920 + t;
            __builtin_amdgcn_global_load_lds(
                (const __attribute__((address_space(1))) void*)(src + (size_t)j * 16),
                (__attribute__((address_space(3))) void*)&ldsB[0][(1920 + wave * 64) * 16],
                16, 0, 0);
        }
    } else {
        for (int i = t; i < 64 * 32; i += 320) {
            int pl = i & 63;
            int cg = i >> 6;
            const float* src = cm + (size_t)cg * 8 * NPIX + pl;
            u16x8 pk;
            #pragma unroll
            for (int j = 0; j < 8; ++j) pk[j] = f2bf(src[j * NPIX]);
            *reinterpret_cast<u16x8*>(&ldsB[0][bswz(pl, cg * 16)]) = pk;
        }
    }

    // ---- fg/bg for both rows: lanes 0..15 one cell each, distribute via shfl ----
    float fb0[6] = {0.f,0.f,0.f,0.f,0.f,0.f}, fb1[6] = {0.f,0.f,0.f,0.f,0.f,0.f};
    if (lane < 16) {
        const float* q0 = dbase0 + (size_t)(cell0 + lane) * NCH + 256;
        float4 a = *reinterpret_cast<const float4*>(q0);
        float4 c = *reinterpret_cast<const float4*>(q0 + 4);
        float fs = 0.5f * a.x + 0.5f, bs = 0.5f * c.x + 0.5f;
        fb0[0] = bs * c.y; fb0[1] = bs * c.z; fb0[2] = bs * c.w;
        fb0[3] = fs * a.y - fb0[0]; fb0[4] = fs * a.z - fb0[1]; fb0[5] = fs * a.w - fb0[2];
        const float* q1 = q0 + (size_t)GRID_W * NCH;
        float4 a1 = *reinterpret_cast<const float4*>(q1);
        float4 c1 = *reinterpret_cast<const float4*>(q1 + 4);
        float fs1 = 0.5f * a1.x + 0.5f, bs1 = 0.5f * c1.x + 0.5f;
        fb1[0] = bs1 * c1.y; fb1[1] = bs1 * c1.z; fb1[2] = bs1 * c1.w;
        fb1[3] = fs1 * a1.y - fb1[0]; fb1[4] = fs1 * a1.z - fb1[1]; fb1[5] = fs1 * a1.w - fb1[2];
    }
    float bgv0[4][3], dv0[4][3], bgv1[4][3], dv1[4][3];
    #pragma unroll
    for (int r = 0; r < 4; ++r) {
        int srcl = g * 4 + r;
        #pragma unroll
        for (int j = 0; j < 3; ++j) {
            bgv0[r][j] = __shfl(fb0[j], srcl);
            dv0[r][j]  = __shfl(fb0[3 + j], srcl);
            bgv1[r][j] = __shfl(fb1[j], srcl);
            dv1[r][j]  = __shfl(fb1[3 + j], srcl);
        }
    }

    // ---- load + pack A for both rows (full K=256): 2 x 8 x bf16x8 ----
    const float* arow0 = dbase0 + (size_t)(cell0 + mrow) * NCH + g * 8;
    const float* arow1 = arow0 + (size_t)GRID_W * NCH;
    short8 apk0[8], apk1[8];
    #pragma unroll
    for (int ks = 0; ks < 8; ++ks) {
        float4 a0 = *reinterpret_cast<const float4*>(arow0 + ks * 32);
        float4 a1 = *reinterpret_cast<const float4*>(arow0 + ks * 32 + 4);
        u16x8 ap;
        ap[0]=f2bf(a0.x); ap[1]=f2bf(a0.y); ap[2]=f2bf(a0.z); ap[3]=f2bf(a0.w);
        ap[4]=f2bf(a1.x); ap[5]=f2bf(a1.y); ap[6]=f2bf(a1.z); ap[7]=f2bf(a1.w);
        apk0[ks] = __builtin_bit_cast(short8, ap);
        float4 b0 = *reinterpret_cast<const float4*>(arow1 + ks * 32);
        float4 b1 = *reinterpret_cast<const float4*>(arow1 + ks * 32 + 4);
        u16x8 bp;
        bp[0]=f2bf(b0.x); bp[1]=f2bf(b0.y); bp[2]=f2bf(b0.z); bp[3]=f2bf(b0.w);
        bp[4]=f2bf(b1.x); bp[5]=f2bf(b1.y); bp[6]=f2bf(b1.z); bp[7]=f2bf(b1.w);
        apk1[ks] = __builtin_bit_cast(short8, bp);
    }

    f32x4 acc0[8], acc1[8];
    #pragma unroll
    for (int n = 0; n < 8; ++n) {
        acc0[n] = (f32x4){0.f, 0.f, 0.f, 0.f};
        acc1[n] = (f32x4){0.f, 0.f, 0.f, 0.f};
    }

    __syncthreads();   // bar#1: buf0 DMA + A/fgbg loads drained

    // ---- issue DMA for half 1 -> buf1, then GEMM half 0 (both rows) ----
    if (USE_WS) {
        const char* src = (const char*)ws + 32768;
        #pragma unroll
        for (int it = 0; it < 6; ++it) {
            int j = it * 320 + t;
            __builtin_amdgcn_global_load_lds(
                (const __attribute__((address_space(1))) void*)(src + (size_t)j * 16),
                (__attribute__((address_space(3))) void*)&ldsB[1][(it * 320 + wave * 64) * 16],
                16, 0, 0);
        }
        if (t < 128) {
            int j = 1920 + t;
            __builtin_amdgcn_global_load_lds(
                (const __attribute__((address_space(1))) void*)(src + (size_t)j * 16),
                (__attribute__((address_space(3))) void*)&ldsB[1][(1920 + wave * 64) * 16],
                16, 0, 0);
        }
    } else {
        for (int i = t; i < 64 * 32; i += 320) {
            int pl = i & 63;
            int cg = i >> 6;
            const float* src = cm + (size_t)cg * 8 * NPIX + 64 + pl;
            u16x8 pk;
            #pragma unroll
            for (int j = 0; j < 8; ++j) pk[j] = f2bf(src[j * NPIX]);
            *reinterpret_cast<u16x8*>(&ldsB[1][bswz(pl, cg * 16)]) = pk;
        }
    }

    #pragma unroll
    for (int ks = 0; ks < 8; ++ks) {
        const int kbase = ks * 32 + g * 8;
        #pragma unroll
        for (int n = 0; n < 4; ++n) {
            int pl = n * 16 + mrow;
            short8 bfrag = *reinterpret_cast<short8*>(&ldsB[0][bswz(pl, kbase * 2)]);
            acc0[n] = __builtin_amdgcn_mfma_f32_16x16x32_bf16(apk0[ks], bfrag, acc0[n], 0, 0, 0);
            acc1[n] = __builtin_amdgcn_mfma_f32_16x16x32_bf16(apk1[ks], bfrag, acc1[n], 0, 0, 0);
        }
    }

    __syncthreads();   // bar#2: buf1 DMA drained (buf0 reads done in-wave)

    #pragma unroll
    for (int ks = 0; ks < 8; ++ks) {
        const int kbase = ks * 32 + g * 8;
        #pragma unroll
        for (int n = 0; n < 4; ++n) {
            int pl = n * 16 + mrow;
            short8 bfrag = *reinterpret_cast<short8*>(&ldsB[1][bswz(pl, kbase * 2)]);
            acc0[4 + n] = __builtin_amdgcn_mfma_f32_16x16x32_bf16(apk0[ks], bfrag, acc0[4 + n], 0, 0, 0);
            acc1[4 + n] = __builtin_amdgcn_mfma_f32_16x16x32_bf16(apk1[ks], bfrag, acc1[4 + n], 0, 0, 0);
        }
    }

    // ---- epilogue (R16-proven) for row0 then row1: wave-private S + NT ----
    const int col = lane & 15;
    f32x4* out4 = (f32x4*)out;
    const int line_sel = col >> 3;
    const int x3 = (col & 7) * 3;
    const f32x4* Sw = (const f32x4*)&S[wave][0][0][0];   // 192 f32x4

    #pragma unroll
    for (int row = 0; row < 2; ++row) {
        const size_t rowf4 = (size_t)(b * 320 + (h0 + row) * 16) * 480 + wave * 96;
        #pragma unroll
        for (int pass = 0; pass < 8; ++pass) {
            #pragma unroll
            for (int r = 0; r < 4; ++r) {
                float raw = row == 0 ? acc0[pass][r] : acc1[pass][r];
                float bgr = row == 0 ? bgv0[r][0] : bgv1[r][0];
                float bgg = row == 0 ? bgv0[r][1] : bgv1[r][1];
                float bgb = row == 0 ? bgv0[r][2] : bgv1[r][2];
                float d0  = row == 0 ? dv0[r][0]  : dv1[r][0];
                float d1  = row == 0 ? dv0[r][1]  : dv1[r][1];
                float d2  = row == 0 ? dv0[r][2]  : dv1[r][2];
                float* o = &S[wave][line_sel][r * 4 + g][x3];
                o[0] = bgr + raw * d0;
                o[1] = bgg + raw * d1;
                o[2] = bgb + raw * d2;
            }
            #pragma unroll
            for (int q = 0; q < 3; ++q) {
                int j = q * 64 + lane;            // 0..191
                int line = (j >= 96) ? 1 : 0;
                int rem = j - 96 * line;          // 0..95 = cell*6 + s
                int c = rem / 6;
                int s = rem - 6 * c;
                f32x4 v = Sw[line * 96 + ((c & 3) * 4 + (c >> 2)) * 6 + s];
                __builtin_nontemporal_store(
                    v, &out4[rowf4 + (size_t)(pass * 2 + line) * 480 + rem]);
            }
        }
    }
}

extern "C" void kernel_launch(void* const* d_in, const int* in_sizes, int n_in,
                              void* d_out, int out_size, void* d_ws, size_t ws_size,
                              hipStream_t stream) {
    (void)in_sizes; (void)n_in; (void)out_size;
    const float* data = (const float*)d_in[0];
    const float* cm   = (const float*)d_in[1];
    float* out        = (float*)d_out;
    const int nblocks = 128 * (GRID_H / 2);   // 1280: one per (b, row-pair)
    if (ws_size >= 65536) {
        prep_kernel<<<16, 256, 0, stream>>>(cm, (unsigned short*)d_ws);
        ansi_kernel<true><<<nblocks, 320, 0, stream>>>(
            data, cm, (const unsigned short*)d_ws, out);
    } else {
        ansi_kernel<false><<<nblocks, 320, 0, stream>>>(data, cm, nullptr, out);
    }
}

// Round 19
// 101.677 us; speedup vs baseline: 1.0152x; 1.0152x over previous
//
#include <hip/hip_runtime.h>

#define GRID_H 20
#define GRID_W 80
#define NCH 264
#define K 256
#define NPIX 128   // 16x8 glyph pixels

typedef __attribute__((ext_vector_type(8))) short short8;
typedef __attribute__((ext_vector_type(4))) float f32x4;
typedef __attribute__((ext_vector_type(8))) unsigned short u16x8;

static __device__ __forceinline__ unsigned short f2bf(float f) {
    unsigned int u = __builtin_bit_cast(unsigned int, f);
    u += 0x7FFFu + ((u >> 16) & 1u);   // round-to-nearest-even
    return (unsigned short)(u >> 16);
}

// Swizzled byte offset within a 32KB pixel-half (R9/R12-proven layout):
// 64 rows (local pixel) x 512B (256 bf16 channels), XOR (pl&7)<<4.
static __device__ __forceinline__ int bswz(int pl, int clbyte) {
    return (pl * 512 + clbyte) ^ ((pl & 7) << 4);
}

// Pack cm (f32 [256 ch][128 px]) -> ws: two 32KB pixel-halves whose LINEAR
// byte order equals the main kernel's swizzled LDS layout (R12/R16-proven).
__global__ void prep_kernel(const float* __restrict__ cm,
                            unsigned short* __restrict__ ws) {
    int i = blockIdx.x * 256 + threadIdx.x;   // 0..4095 chunks of 16B
    int p  = i & 127;                         // pixel 0..127
    int c8 = i >> 7;                          // channel-group of 8 (0..31)
    int hf = p >> 6, pl = p & 63;
    u16x8 pk;
    #pragma unroll
    for (int j = 0; j < 8; ++j) pk[j] = f2bf(cm[(c8 * 8 + j) * NPIX + p]);
    *reinterpret_cast<u16x8*>((char*)ws + hf * 32768 + bswz(pl, c8 * 16)) = pk;
}

// NOTE: plain 1-arg launch_bounds only. The 2-arg form (min waves/EU)
// miscompiled MFMA accumulation in R2/R3/R7. Every global_load_lds batch
// must have its own nearby following barrier before consumption (R17 raced
// with one distant barrier); depth <=7 outstanding per thread (R18-proven).
template <bool USE_WS>
__global__ __launch_bounds__(320) void ansi_kernel(
        const float* __restrict__ data,
        const float* __restrict__ cm,
        const unsigned short* __restrict__ ws,
        float* __restrict__ out) {
    // Double-buffered pixel-halves of B: half-1 DMA overlaps half-0 MFMA.
    __shared__ alignas(16) unsigned char ldsB[2][32768];
    // Wave-PRIVATE epilogue staging (R9-proven): [wave][line][slot][x*3+ch]
    __shared__ alignas(16) float S[5][2][16][24];   // 15 KB; total ~80 KB

    const int blk = blockIdx.x;
    const int b = blk / GRID_H;
    const int h = blk % GRID_H;
    const float* dbase = data + (size_t)(b * GRID_H + h) * GRID_W * NCH;
    const int t = threadIdx.x;
    const int wave = t >> 6;
    const int lane = t & 63;
    const int mrow = lane & 15;     // cell within M-tile
    const int g    = lane >> 4;     // k-group
    const int cell0 = wave * 16;

    // ---- issue DMA half0 -> buf0 (R12-proven shape) ----
    if (USE_WS) {
        const char* src = (const char*)ws;
        #pragma unroll
        for (int it = 0; it < 6; ++it) {
            int j = it * 320 + t;
            __builtin_amdgcn_global_load_lds(
                (const __attribute__((address_space(1))) void*)(src + (size_t)j * 16),
                (__attribute__((address_space(3))) void*)&ldsB[0][(it * 320 + wave * 64) * 16],
                16, 0, 0);
        }
        if (t < 128) {   // tail chunks 1920..2047 (waves 0,1 full)
            int j = 1920 + t;
            __builtin_amdgcn_global_load_lds(
                (const __attribute__((address_space(1))) void*)(src + (size_t)j * 16),
                (__attribute__((address_space(3))) void*)&ldsB[0][(1920 + wave * 64) * 16],
                16, 0, 0);
        }
    } else {
        for (int i = t; i < 64 * 32; i += 320) {
            int pl = i & 63;
            int cg = i >> 6;
            const float* src = cm + (size_t)cg * 8 * NPIX + pl;
            u16x8 pk;
            #pragma unroll
            for (int j = 0; j < 8; ++j) pk[j] = f2bf(src[j * NPIX]);
            *reinterpret_cast<u16x8*>(&ldsB[0][bswz(pl, cg * 16)]) = pk;
        }
    }

    // ---- fg/bg: lanes 0..15 one cell each, distribute via shfl ----
    float fb[6] = {0.f, 0.f, 0.f, 0.f, 0.f, 0.f};
    if (lane < 16) {
        const float* q = dbase + (size_t)(cell0 + lane) * NCH + 256;
        float4 a = *reinterpret_cast<const float4*>(q);      // fg_bold, fg.rgb
        float4 c = *reinterpret_cast<const float4*>(q + 4);  // bg_bold, bg.rgb
        float fs = 0.5f * a.x + 0.5f;
        float bs = 0.5f * c.x + 0.5f;
        fb[0] = bs * c.y; fb[1] = bs * c.z; fb[2] = bs * c.w;
        fb[3] = fs * a.y - fb[0];
        fb[4] = fs * a.z - fb[1];
        fb[5] = fs * a.w - fb[2];
    }
    float bgv[4][3], dv[4][3];
    #pragma unroll
    for (int r = 0; r < 4; ++r) {
        int srcl = g * 4 + r;        // source lane = local cell index
        #pragma unroll
        for (int j = 0; j < 3; ++j) {
            bgv[r][j] = __shfl(fb[j], srcl);
            dv[r][j]  = __shfl(fb[3 + j], srcl);
        }
    }

    // ---- load + pack A once (full K=256): 8 x bf16x8 ----
    const float* arow = dbase + (size_t)(cell0 + mrow) * NCH + g * 8;
    short8 apk[8];
    #pragma unroll
    for (int ks = 0; ks < 8; ++ks) {
        float4 a0 = *reinterpret_cast<const float4*>(arow + ks * 32);
        float4 a1 = *reinterpret_cast<const float4*>(arow + ks * 32 + 4);
        u16x8 ap;
        ap[0] = f2bf(a0.x); ap[1] = f2bf(a0.y); ap[2] = f2bf(a0.z); ap[3] = f2bf(a0.w);
        ap[4] = f2bf(a1.x); ap[5] = f2bf(a1.y); ap[6] = f2bf(a1.z); ap[7] = f2bf(a1.w);
        apk[ks] = __builtin_bit_cast(short8, ap);
    }

    f32x4 acc[8];
    #pragma unroll
    for (int n = 0; n < 8; ++n) acc[n] = (f32x4){0.f, 0.f, 0.f, 0.f};

    __syncthreads();   // bar#1: buf0 DMA + A/fgbg loads drained

    // ---- issue DMA half1 -> buf1 (flies under the half0 MFMAs) ----
    if (USE_WS) {
        const char* src = (const char*)ws + 32768;
        #pragma unroll
        for (int it = 0; it < 6; ++it) {
            int j = it * 320 + t;
            __builtin_amdgcn_global_load_lds(
                (const __attribute__((address_space(1))) void*)(src + (size_t)j * 16),
                (__attribute__((address_space(3))) void*)&ldsB[1][(it * 320 + wave * 64) * 16],
                16, 0, 0);
        }
        if (t < 128) {
            int j = 1920 + t;
            __builtin_amdgcn_global_load_lds(
                (const __attribute__((address_space(1))) void*)(src + (size_t)j * 16),
                (__attribute__((address_space(3))) void*)&ldsB[1][(1920 + wave * 64) * 16],
                16, 0, 0);
        }
    } else {
        for (int i = t; i < 64 * 32; i += 320) {
            int pl = i & 63;
            int cg = i >> 6;
            const float* src = cm + (size_t)cg * 8 * NPIX + 64 + pl;
            u16x8 pk;
            #pragma unroll
            for (int j = 0; j < 8; ++j) pk[j] = f2bf(src[j * NPIX]);
            *reinterpret_cast<u16x8*>(&ldsB[1][bswz(pl, cg * 16)]) = pk;
        }
    }

    // ---- GEMM half0 from buf0 ----
    #pragma unroll
    for (int ks = 0; ks < 8; ++ks) {
        const int kbase = ks * 32 + g * 8;
        #pragma unroll
        for (int n = 0; n < 4; ++n) {
            int pl = n * 16 + mrow;
            short8 bfrag = *reinterpret_cast<short8*>(&ldsB[0][bswz(pl, kbase * 2)]);
            acc[n] = __builtin_amdgcn_mfma_f32_16x16x32_bf16(
                apk[ks], bfrag, acc[n], 0, 0, 0);
        }
    }

    __syncthreads();   // bar#2: buf1 DMA drained

    // ---- GEMM half1 from buf1 ----
    #pragma unroll
    for (int ks = 0; ks < 8; ++ks) {
        const int kbase = ks * 32 + g * 8;
        #pragma unroll
        for (int n = 0; n < 4; ++n) {
            int pl = n * 16 + mrow;
            short8 bfrag = *reinterpret_cast<short8*>(&ldsB[1][bswz(pl, kbase * 2)]);
            acc[4 + n] = __builtin_amdgcn_mfma_f32_16x16x32_bf16(
                apk[ks], bfrag, acc[4 + n], 0, 0, 0);
        }
    }

    // ---- epilogue (R16-proven): wave-private LDS transpose + NT stores ----
    const int col = lane & 15;
    f32x4* out4 = (f32x4*)out;          // ext_vector type for NT builtin
    const size_t rowf4 = (size_t)(b * 320 + h * 16) * 480 + wave * 96;
    const int line_sel = col >> 3;
    const int x3 = (col & 7) * 3;

    #pragma unroll
    for (int pass = 0; pass < 8; ++pass) {
        #pragma unroll
        for (int r = 0; r < 4; ++r) {
            float raw = acc[pass][r];
            float* o = &S[wave][line_sel][r * 4 + g][x3];
            o[0] = bgv[r][0] + raw * dv[r][0];
            o[1] = bgv[r][1] + raw * dv[r][1];
            o[2] = bgv[r][2] + raw * dv[r][2];
        }
        const f32x4* Sw = (const f32x4*)&S[wave][0][0][0];   // 192 f32x4
        #pragma unroll
        for (int q = 0; q < 3; ++q) {
            int j = q * 64 + lane;            // 0..191
            int line = (j >= 96) ? 1 : 0;
            int rem = j - 96 * line;          // 0..95 = cell*6 + s
            int c = rem / 6;
            int s = rem - 6 * c;
            f32x4 v = Sw[line * 96 + ((c & 3) * 4 + (c >> 2)) * 6 + s];
            __builtin_nontemporal_store(
                v, &out4[rowf4 + (size_t)(pass * 2 + line) * 480 + rem]);
        }
    }
}

extern "C" void kernel_launch(void* const* d_in, const int* in_sizes, int n_in,
                              void* d_out, int out_size, void* d_ws, size_t ws_size,
                              hipStream_t stream) {
    (void)in_sizes; (void)n_in; (void)out_size;
    const float* data = (const float*)d_in[0];
    const float* cm   = (const float*)d_in[1];
    float* out        = (float*)d_out;
    const int nblocks = 128 * GRID_H;   // one block per (b, h)
    if (ws_size >= 65536) {
        prep_kernel<<<16, 256, 0, stream>>>(cm, (unsigned short*)d_ws);
        ansi_kernel<true><<<nblocks, 320, 0, stream>>>(
            data, cm, (const unsigned short*)d_ws, out);
    } else {
        ansi_kernel<false><<<nblocks, 320, 0, stream>>>(data, cm, nullptr, out);
    }
}

// Round 20
// 97.802 us; speedup vs baseline: 1.0554x; 1.0396x over previous
//
#include <hip/hip_runtime.h>

#define GRID_H 20
#define GRID_W 80
#define NCH 264
#define K 256
#define NPIX 128   // 16x8 glyph pixels

typedef __attribute__((ext_vector_type(8))) short short8;
typedef __attribute__((ext_vector_type(4))) float f32x4;
typedef __attribute__((ext_vector_type(8))) unsigned short u16x8;

static __device__ __forceinline__ unsigned short f2bf(float f) {
    unsigned int u = __builtin_bit_cast(unsigned int, f);
    u += 0x7FFFu + ((u >> 16) & 1u);   // round-to-nearest-even
    return (unsigned short)(u >> 16);
}

// Swizzled byte offset within a 32KB pixel-half (R9/R12-proven layout):
// 64 rows (local pixel) x 512B (256 bf16 channels), XOR (pl&7)<<4.
static __device__ __forceinline__ int bswz(int pl, int clbyte) {
    return (pl * 512 + clbyte) ^ ((pl & 7) << 4);
}

// Pack cm (f32 [256 ch][128 px]) -> ws: two 32KB pixel-halves whose LINEAR
// byte order equals the main kernel's swizzled LDS layout (R12/R16-proven).
__global__ void prep_kernel(const float* __restrict__ cm,
                            unsigned short* __restrict__ ws) {
    int i = blockIdx.x * 256 + threadIdx.x;   // 0..4095 chunks of 16B
    int p  = i & 127;                         // pixel 0..127
    int c8 = i >> 7;                          // channel-group of 8 (0..31)
    int hf = p >> 6, pl = p & 63;
    u16x8 pk;
    #pragma unroll
    for (int j = 0; j < 8; ++j) pk[j] = f2bf(cm[(c8 * 8 + j) * NPIX + p]);
    *reinterpret_cast<u16x8*>((char*)ws + hf * 32768 + bswz(pl, c8 * 16)) = pk;
}

// NOTE: plain 1-arg launch_bounds only (2-arg form miscompiled MFMA, R2/R3/R7).
// Every global_load_lds batch gets its own nearby following barrier (R17 race).
template <bool USE_WS>
__global__ __launch_bounds__(320) void ansi_kernel(
        const float* __restrict__ data,
        const float* __restrict__ cm,
        const unsigned short* __restrict__ ws,
        float* __restrict__ out) {
    // Double-buffered pixel-halves of B: half-1 DMA overlaps half-0 MFMA.
    __shared__ alignas(16) unsigned char ldsB[2][32768];
    // Wave-PRIVATE epilogue staging (R9-proven): [wave][line][slot][x*3+ch]
    __shared__ alignas(16) float S[5][2][16][24];   // 15 KB; total ~80 KB

    const int blk = blockIdx.x;
    const int b = blk / GRID_H;
    const int h = blk % GRID_H;
    const float* dbase = data + (size_t)(b * GRID_H + h) * GRID_W * NCH;
    const int t = threadIdx.x;
    const int wave = t >> 6;
    const int lane = t & 63;
    const int mrow = lane & 15;     // cell within M-tile
    const int g    = lane >> 4;     // k-group
    const int cell0 = wave * 16;

    // ---- issue DMA half0 -> buf0 (R12-proven shape) ----
    if (USE_WS) {
        const char* src = (const char*)ws;
        #pragma unroll
        for (int it = 0; it < 6; ++it) {
            int j = it * 320 + t;
            __builtin_amdgcn_global_load_lds(
                (const __attribute__((address_space(1))) void*)(src + (size_t)j * 16),
                (__attribute__((address_space(3))) void*)&ldsB[0][(it * 320 + wave * 64) * 16],
                16, 0, 0);
        }
        if (t < 128) {   // tail chunks 1920..2047 (waves 0,1 full)
            int j = 1920 + t;
            __builtin_amdgcn_global_load_lds(
                (const __attribute__((address_space(1))) void*)(src + (size_t)j * 16),
                (__attribute__((address_space(3))) void*)&ldsB[0][(1920 + wave * 64) * 16],
                16, 0, 0);
        }
    } else {
        for (int i = t; i < 64 * 32; i += 320) {
            int pl = i & 63;
            int cg = i >> 6;
            const float* src = cm + (size_t)cg * 8 * NPIX + pl;
            u16x8 pk;
            #pragma unroll
            for (int j = 0; j < 8; ++j) pk[j] = f2bf(src[j * NPIX]);
            *reinterpret_cast<u16x8*>(&ldsB[0][bswz(pl, cg * 16)]) = pk;
        }
    }

    // ---- fg/bg: lanes 0..15 one cell each, distribute via shfl ----
    float fb[6] = {0.f, 0.f, 0.f, 0.f, 0.f, 0.f};
    if (lane < 16) {
        const float* q = dbase + (size_t)(cell0 + lane) * NCH + 256;
        float4 a = *reinterpret_cast<const float4*>(q);      // fg_bold, fg.rgb
        float4 c = *reinterpret_cast<const float4*>(q + 4);  // bg_bold, bg.rgb
        float fs = 0.5f * a.x + 0.5f;
        float bs = 0.5f * c.x + 0.5f;
        fb[0] = bs * c.y; fb[1] = bs * c.z; fb[2] = bs * c.w;
        fb[3] = fs * a.y - fb[0];
        fb[4] = fs * a.z - fb[1];
        fb[5] = fs * a.w - fb[2];
    }
    float bgv[4][3], dv[4][3];
    #pragma unroll
    for (int r = 0; r < 4; ++r) {
        int srcl = g * 4 + r;        // source lane = local cell index
        #pragma unroll
        for (int j = 0; j < 3; ++j) {
            bgv[r][j] = __shfl(fb[j], srcl);
            dv[r][j]  = __shfl(fb[3 + j], srcl);
        }
    }

    // ---- load + pack A once (full K=256): 8 x bf16x8 ----
    const float* arow = dbase + (size_t)(cell0 + mrow) * NCH + g * 8;
    short8 apk[8];
    #pragma unroll
    for (int ks = 0; ks < 8; ++ks) {
        float4 a0 = *reinterpret_cast<const float4*>(arow + ks * 32);
        float4 a1 = *reinterpret_cast<const float4*>(arow + ks * 32 + 4);
        u16x8 ap;
        ap[0] = f2bf(a0.x); ap[1] = f2bf(a0.y); ap[2] = f2bf(a0.z); ap[3] = f2bf(a0.w);
        ap[4] = f2bf(a1.x); ap[5] = f2bf(a1.y); ap[6] = f2bf(a1.z); ap[7] = f2bf(a1.w);
        apk[ks] = __builtin_bit_cast(short8, ap);
    }

    f32x4 acc[8];
    #pragma unroll
    for (int n = 0; n < 8; ++n) acc[n] = (f32x4){0.f, 0.f, 0.f, 0.f};

    __syncthreads();   // bar#1: buf0 DMA + A/fgbg loads drained

    // ---- issue DMA half1 -> buf1 (flies under the half0 MFMAs) ----
    if (USE_WS) {
        const char* src = (const char*)ws + 32768;
        #pragma unroll
        for (int it = 0; it < 6; ++it) {
            int j = it * 320 + t;
            __builtin_amdgcn_global_load_lds(
                (const __attribute__((address_space(1))) void*)(src + (size_t)j * 16),
                (__attribute__((address_space(3))) void*)&ldsB[1][(it * 320 + wave * 64) * 16],
                16, 0, 0);
        }
        if (t < 128) {
            int j = 1920 + t;
            __builtin_amdgcn_global_load_lds(
                (const __attribute__((address_space(1))) void*)(src + (size_t)j * 16),
                (__attribute__((address_space(3))) void*)&ldsB[1][(1920 + wave * 64) * 16],
                16, 0, 0);
        }
    } else {
        for (int i = t; i < 64 * 32; i += 320) {
            int pl = i & 63;
            int cg = i >> 6;
            const float* src = cm + (size_t)cg * 8 * NPIX + 64 + pl;
            u16x8 pk;
            #pragma unroll
            for (int j = 0; j < 8; ++j) pk[j] = f2bf(src[j * NPIX]);
            *reinterpret_cast<u16x8*>(&ldsB[1][bswz(pl, cg * 16)]) = pk;
        }
    }

    // ---- GEMM half0 from buf0 ----
    #pragma unroll
    for (int ks = 0; ks < 8; ++ks) {
        const int kbase = ks * 32 + g * 8;
        #pragma unroll
        for (int n = 0; n < 4; ++n) {
            int pl = n * 16 + mrow;
            short8 bfrag = *reinterpret_cast<short8*>(&ldsB[0][bswz(pl, kbase * 2)]);
            acc[n] = __builtin_amdgcn_mfma_f32_16x16x32_bf16(
                apk[ks], bfrag, acc[n], 0, 0, 0);
        }
    }

    __syncthreads();   // bar#2: buf1 DMA drained

    // ---- epilogue setup (R16-proven mapping) ----
    const int col = lane & 15;
    f32x4* out4 = (f32x4*)out;          // ext_vector type for NT builtin
    const size_t rowf4 = (size_t)(b * 320 + h * 16) * 480 + wave * 96;
    const int line_sel = col >> 3;
    const int x3 = (col & 7) * 3;
    const f32x4* Sw = (const f32x4*)&S[wave][0][0][0];   // 192 f32x4

    // ---- EPILOGUE FIRST HALF (passes 0..3, acc[0..3] final): these 24 NT
    // stores/thread drain UNDER the half1 GEMM below (store pipe || MFMA).
    #pragma unroll
    for (int pass = 0; pass < 4; ++pass) {
        #pragma unroll
        for (int r = 0; r < 4; ++r) {
            float raw = acc[pass][r];
            float* o = &S[wave][line_sel][r * 4 + g][x3];
            o[0] = bgv[r][0] + raw * dv[r][0];
            o[1] = bgv[r][1] + raw * dv[r][1];
            o[2] = bgv[r][2] + raw * dv[r][2];
        }
        #pragma unroll
        for (int q = 0; q < 3; ++q) {
            int j = q * 64 + lane;            // 0..191
            int line = (j >= 96) ? 1 : 0;
            int rem = j - 96 * line;          // 0..95 = cell*6 + s
            int c = rem / 6;
            int s = rem - 6 * c;
            f32x4 v = Sw[line * 96 + ((c & 3) * 4 + (c >> 2)) * 6 + s];
            __builtin_nontemporal_store(
                v, &out4[rowf4 + (size_t)(pass * 2 + line) * 480 + rem]);
        }
    }

    // ---- GEMM half1 from buf1 ----
    #pragma unroll
    for (int ks = 0; ks < 8; ++ks) {
        const int kbase = ks * 32 + g * 8;
        #pragma unroll
        for (int n = 0; n < 4; ++n) {
            int pl = n * 16 + mrow;
            short8 bfrag = *reinterpret_cast<short8*>(&ldsB[1][bswz(pl, kbase * 2)]);
            acc[4 + n] = __builtin_amdgcn_mfma_f32_16x16x32_bf16(
                apk[ks], bfrag, acc[4 + n], 0, 0, 0);
        }
    }

    // ---- EPILOGUE SECOND HALF (passes 4..7) ----
    #pragma unroll
    for (int pass = 4; pass < 8; ++pass) {
        #pragma unroll
        for (int r = 0; r < 4; ++r) {
            float raw = acc[pass][r];
            float* o = &S[wave][line_sel][r * 4 + g][x3];
            o[0] = bgv[r][0] + raw * dv[r][0];
            o[1] = bgv[r][1] + raw * dv[r][1];
            o[2] = bgv[r][2] + raw * dv[r][2];
        }
        #pragma unroll
        for (int q = 0; q < 3; ++q) {
            int j = q * 64 + lane;            // 0..191
            int line = (j >= 96) ? 1 : 0;
            int rem = j - 96 * line;          // 0..95 = cell*6 + s
            int c = rem / 6;
            int s = rem - 6 * c;
            f32x4 v = Sw[line * 96 + ((c & 3) * 4 + (c >> 2)) * 6 + s];
            __builtin_nontemporal_store(
                v, &out4[rowf4 + (size_t)(pass * 2 + line) * 480 + rem]);
        }
    }
}

extern "C" void kernel_launch(void* const* d_in, const int* in_sizes, int n_in,
                              void* d_out, int out_size, void* d_ws, size_t ws_size,
                              hipStream_t stream) {
    (void)in_sizes; (void)n_in; (void)out_size;
    const float* data = (const float*)d_in[0];
    const float* cm   = (const float*)d_in[1];
    float* out        = (float*)d_out;
    const int nblocks = 128 * GRID_H;   // one block per (b, h)
    if (ws_size >= 65536) {
        prep_kernel<<<16, 256, 0, stream>>>(cm, (unsigned short*)d_ws);
        ansi_kernel<true><<<nblocks, 320, 0, stream>>>(
            data, cm, (const unsigned short*)d_ws, out);
    } else {
        ansi_kernel<false><<<nblocks, 320, 0, stream>>>(data, cm, nullptr, out);
    }
}